// Round 6
// baseline (563.464 us; speedup 1.0000x reference)
//
#include <hip/hip_runtime.h>

#define D_   1024
#define H_   16
#define DH_  64
#define S_   5
#define W_   128
#define BKB_ 32      // saliency block size
#define DFF_ 4096
#define B_   4
#define L_   2048
#define NB_  64
#define SW_  (S_*W_) // 640

typedef unsigned short u16;  // bf16 bit pattern
typedef __attribute__((ext_vector_type(8))) short short8;
typedef __attribute__((ext_vector_type(4))) float floatx4;

__device__ __forceinline__ u16 f2bf(float f){
  unsigned int u = __float_as_uint(f);
  unsigned int r = 0x7fffu + ((u >> 16) & 1u);
  return (u16)((u + r) >> 16);
}

__device__ __forceinline__ void async_copy16(const u16* g, u16* lds){
  __builtin_amdgcn_global_load_lds(
      (const __attribute__((address_space(1))) void*)g,
      (__attribute__((address_space(3))) void*)lds, 16, 0, 0);
}

// gelu(x) = 0.5x(1+tanh(u)) = x*t/(t+1), t = exp(2u); branch-free
__device__ __forceinline__ float gelu_fast(float x){
  float u2 = 1.5957691216057308f * x * __builtin_fmaf(0.044715f, x*x, 1.0f);
  u2 = fminf(u2, 20.0f);
  float t = __expf(u2);
  return x * t * __builtin_amdgcn_rcpf(t + 1.0f);
}

// ---------------- weight prep ----------------
__global__ void cast_f32_to_bf16(const float* __restrict__ in, u16* __restrict__ out, int n4){
  int i = blockIdx.x*256 + threadIdx.x;
  if (i < n4){
    float4 v = reinterpret_cast<const float4*>(in)[i];
    uint2 p;
    p.x = (unsigned)f2bf(v.x) | ((unsigned)f2bf(v.y) << 16);
    p.y = (unsigned)f2bf(v.z) | ((unsigned)f2bf(v.w) << 16);
    reinterpret_cast<uint2*>(out)[i] = p;
  }
}

// out[c][r] = in[r][c], out bf16 (C x R), in f32 (R x C)
__global__ void transpose_cast(const float* __restrict__ in, u16* __restrict__ out, int R, int C){
  __shared__ float t[32][33];
  int bx = blockIdx.x*32, by = blockIdx.y*32;
  int x = threadIdx.x & 31, y = threadIdx.x >> 5;   // y in 0..7
  #pragma unroll
  for (int i=0;i<4;i++)
    t[y + i*8][x] = in[(long long)(by + y + i*8)*C + bx + x];
  __syncthreads();
  #pragma unroll
  for (int i=0;i<4;i++)
    out[(long long)(bx + y + i*8)*R + by + x] = f2bf(t[x][y + i*8]);
}

// ---------------- layernorm (+ optional saliency row-dot) ----------------
template<bool ROWDOT>
__global__ __launch_bounds__(256) void ln_kernel(
    const float* __restrict__ x, const float* __restrict__ g, const float* __restrict__ b,
    const float* __restrict__ wsal, u16* __restrict__ out, float* __restrict__ logits)
{
  __shared__ float red[8];
  int row = blockIdx.x;
  int t = threadIdx.x;
  const float* xr = x + (long long)row*D_;
  float4 v = reinterpret_cast<const float4*>(xr)[t];
  float s  = v.x+v.y+v.z+v.w;
  float sq = v.x*v.x+v.y*v.y+v.z*v.z+v.w*v.w;
  #pragma unroll
  for (int m=32;m>=1;m>>=1){ s += __shfl_xor(s,m); sq += __shfl_xor(sq,m); }
  int wid = t>>6;
  if ((t&63)==0){ red[wid]=s; red[wid+4]=sq; }
  __syncthreads();
  s  = red[0]+red[1]+red[2]+red[3];
  sq = red[4]+red[5]+red[6]+red[7];
  float mean = s * (1.0f/D_);
  float var  = sq * (1.0f/D_) - mean*mean;
  float rstd = rsqrtf(fmaxf(var,0.0f) + 1e-5f);
  float4 gg = reinterpret_cast<const float4*>(g)[t];
  float4 bb = reinterpret_cast<const float4*>(b)[t];
  float h0 = (v.x-mean)*rstd*gg.x + bb.x;
  float h1 = (v.y-mean)*rstd*gg.y + bb.y;
  float h2 = (v.z-mean)*rstd*gg.z + bb.z;
  float h3 = (v.w-mean)*rstd*gg.w + bb.w;
  uint2 p;
  p.x = (unsigned)f2bf(h0) | ((unsigned)f2bf(h1) << 16);
  p.y = (unsigned)f2bf(h2) | ((unsigned)f2bf(h3) << 16);
  reinterpret_cast<uint2*>(out + (long long)row*D_)[t] = p;
  if (ROWDOT){
    float4 ww = reinterpret_cast<const float4*>(wsal)[t];
    float d = h0*ww.x + h1*ww.y + h2*ww.z + h3*ww.w;
    #pragma unroll
    for (int m=32;m>=1;m>>=1) d += __shfl_xor(d,m);
    __syncthreads();                     // red[] reuse guard
    if ((t&63)==0) red[wid] = d;
    __syncthreads();
    if (t==0)
      atomicAdd(logits + (row>>5), (red[0]+red[1]+red[2]+red[3]) * (1.0f/BKB_));
  }
}

// ---------------- gumbel argmax selection ----------------
__global__ void select_kernel(const float* __restrict__ logits, const float* __restrict__ gum,
                              const float* __restrict__ bsal, int* __restrict__ start)
{
  int s = blockIdx.x >> 2, b = blockIdx.x & 3;
  int n = threadIdx.x;                  // 0..63 (NB)
  float u = gum[(s*B_ + b)*NB_ + n];
  float g = -logf(-logf(u + 1e-9f) + 1e-9f);
  float val = logits[b*NB_ + n] + bsal[0] + g;   // TAU == 1
  int idx = n;
  #pragma unroll
  for (int m=1;m<64;m<<=1){
    float ov = __shfl_xor(val, m);
    int   oi = __shfl_xor(idx, m);
    if (ov > val || (ov == val && oi < idx)) { val = ov; idx = oi; }
  }
  if (n==0){
    int c = idx*BKB_ + BKB_/2 - W_/2;
    c = c < 0 ? 0 : (c > (L_-W_) ? (L_-W_) : c);
    start[blockIdx.x] = c;
  }
}

// ---------------- window gather: kv[b][s*W+w] = h[b][start[s][b]+w] ----------------
__global__ void gather_kv(const u16* __restrict__ h, const int* __restrict__ start, u16* __restrict__ kv){
  int row = blockIdx.x;                  // b*640 + s*128 + w
  int b = row / SW_; int sw = row % SW_; int s = sw >> 7; int w = sw & 127;
  long long src = (long long)(b*L_ + start[s*B_ + b] + w)*D_;
  reinterpret_cast<uint2*>(kv + (long long)row*D_)[threadIdx.x] =
      reinterpret_cast<const uint2*>(h + src)[threadIdx.x];
}

// -------- big-tile NT GEMM: C = A(MxK) * B(NxK)^T, 256x128 block --------
// 2x2 waves, each wave owns a 128x64 tile (acc 8x4): LDS arithmetic intensity
// M_w*N_w/(M_w+N_w) = 42.7 FLOP/B vs 32 for 64x64 — the 64x64 shape was
// LDS-BW-bound at ~30% MfmaUtil (the observed 27%).
// BK=32 ping-pong dbuf, one barrier/iter, next tile issued after the barrier.
// Swizzle: rows are 64B (16 banks), so phys_chunk = logical ^ ((r^(r>>2))&3)
// spreads rows {0,4,8,12} too (round-5's ^(r&3) left a 4-way conflict).
// Staging global_load_lds writes are inherently line-packed (lane*16B).
// EPI: 0 = +bias->bf16 ; 1 = gelu(+bias)->bf16 ; 2 = +bias+res->f32 ;
//      3 = merged KV: col<1024 -> k(+bias)->bf16 ld1024; col>=1024 -> v(+bias)
//          written TRANSPOSED to Cout2 = vT[b][h][dh][m] (packed uint2 stores)
template<int EPI>
__global__ __launch_bounds__(256, 2) void gemm_bt(
    const u16* __restrict__ A, const u16* __restrict__ Bm,
    const float* __restrict__ bias, const float* __restrict__ res,
    void* __restrict__ Cout, void* __restrict__ Cout2, int M, int N, int K)
{
  __shared__ u16 As[2][256*32];
  __shared__ u16 Bs[2][128*32];
  const int tid = threadIdx.x;
  const int wave = tid>>6, lane = tid&63;
  const int wr = wave>>1, wc = wave&1;       // wave tile: rows wr*128, cols wc*64
  const int quad = lane>>4, l16 = lane&15;
  const int rowA0 = blockIdx.x*256;
  const int colB0 = blockIdx.y*128;
  // staging: lane covers row-in-group sub = lane>>2, phys chunk pc = lane&3,
  // sourcing logical chunk lc = pc ^ s(sub) so readers see swizzled layout
  const int sub = lane>>2, pc = lane&3;
  const int lc  = pc ^ ((sub ^ (sub>>2)) & 3);
  const u16* aP = A  + (long long)(rowA0 + wave*64 + sub)*K + lc*8;
  const u16* bP = Bm + (long long)(colB0 + wave*32 + sub)*K + lc*8;
  // fragment-read swizzled chunk offset (s(row) = (l16 ^ (l16>>2)) & 3)
  const int cq = (quad ^ ((l16 ^ (l16>>2)) & 3)) * 8;

  floatx4 acc[8][4];
  #pragma unroll
  for (int i=0;i<8;i++)
    #pragma unroll
    for (int j=0;j<4;j++) acc[i][j] = (floatx4)0.0f;

  const int T = K >> 5;
  // prologue: tile 0 -> buffer 0
  #pragma unroll
  for (int g=0;g<4;g++)
    async_copy16(aP + (long long)g*16*K, &As[0][0] + (wave*64 + g*16)*32);
  #pragma unroll
  for (int g=0;g<2;g++)
    async_copy16(bP + (long long)g*16*K, &Bs[0][0] + (wave*32 + g*16)*32);

  for (int t=0; t<T; ++t){
    __syncthreads();                 // drains tile t; frees buffer (t+1)&1
    if (t+1 < T){
      const int nb = (t+1)&1;
      const long long ko = (long long)(t+1)*32;
      #pragma unroll
      for (int g=0;g<4;g++)
        async_copy16(aP + (long long)g*16*K + ko, &As[nb][0] + (wave*64 + g*16)*32);
      #pragma unroll
      for (int g=0;g<2;g++)
        async_copy16(bP + (long long)g*16*K + ko, &Bs[nb][0] + (wave*32 + g*16)*32);
    }
    const u16* Ab = &As[t&1][0];
    const u16* Bb = &Bs[t&1][0];
    short8 bf[4];
    #pragma unroll
    for (int j=0;j<4;j++)
      bf[j] = *reinterpret_cast<const short8*>(Bb + (wc*64 + j*16 + l16)*32 + cq);
    #pragma unroll
    for (int i=0;i<8;i++){
      short8 af = *reinterpret_cast<const short8*>(Ab + (wr*128 + i*16 + l16)*32 + cq);
      #pragma unroll
      for (int j=0;j<4;j++)
        acc[i][j] = __builtin_amdgcn_mfma_f32_16x16x32_bf16(af, bf[j], acc[i][j], 0,0,0);
    }
  }

  #pragma unroll
  for (int i=0;i<8;i++){
    #pragma unroll
    for (int j=0;j<4;j++){
      int row0 = rowA0 + wr*128 + i*16 + quad*4;
      int col  = colB0 + wc*64 + j*16 + l16;
      float bc = bias[col];
      if (EPI==3){
        if (col < 1024){                       // k-part: ld 1024
          #pragma unroll
          for (int r=0;r<4;r++)
            ((u16*)Cout)[(long long)(row0+r)*1024 + col] = f2bf(acc[i][j][r] + bc);
        } else {                               // v-part: transposed, m-contiguous
          int vcol = col - 1024;
          int h = vcol >> 6, dh = vcol & 63;
          int b = row0 / SW_, mm = row0 % SW_;
          uint2 pk;
          pk.x = (unsigned)f2bf(acc[i][j][0]+bc) | ((unsigned)f2bf(acc[i][j][1]+bc) << 16);
          pk.y = (unsigned)f2bf(acc[i][j][2]+bc) | ((unsigned)f2bf(acc[i][j][3]+bc) << 16);
          *reinterpret_cast<uint2*>((u16*)Cout2 + ((long long)((b*H_ + h)*DH_ + dh))*SW_ + mm) = pk;
        }
      } else {
        #pragma unroll
        for (int r=0;r<4;r++){
          long long cidx = (long long)(row0+r)*N + col;
          float val = acc[i][j][r] + bc;
          if (EPI==0)      ((u16*)Cout)[cidx] = f2bf(val);
          else if (EPI==1) ((u16*)Cout)[cidx] = f2bf(gelu_fast(val));
          else             ((float*)Cout)[cidx] = val + res[cidx];
        }
      }
    }
  }
}

// ---------------- fused flash attention, S^T formulation ----------------
// grid (B*H, L/64); 4 waves, each wave owns 16 q-rows. m-tiles of 64 K/V rows.
__global__ __launch_bounds__(256) void attn_kernel(
    const u16* __restrict__ q, const u16* __restrict__ k, const u16* __restrict__ vT,
    u16* __restrict__ o)
{
  const int bh = blockIdx.x;
  const int b = bh >> 4, h = bh & 15;
  const int tid = threadIdx.x;
  const int wave = tid >> 6, lane = tid & 63;
  const int quad = lane >> 4, l16 = lane & 15;
  const int qrow0 = blockIdx.y*64 + wave*16;

  __shared__ u16 Ks[64*64];      // K rows (m-major, d contiguous, swizzled)
  __shared__ u16 Vs[64*64];      // V^T rows (d-major, m contiguous, swizzled)
  __shared__ u16 Ps[4][16*72];   // per-wave P (q-major, m contiguous, padded)

  // Q fragments (B-operand: lane l16 = q-row, quad*8 = d-chunk)
  const u16* qp = q + ((long long)(b*L_ + qrow0 + l16)*D_ + h*DH_ + quad*8);
  short8 qf0 = *reinterpret_cast<const short8*>(qp);
  short8 qf1 = *reinterpret_cast<const short8*>(qp + 32);

  floatx4 Oacc[4];
  #pragma unroll
  for (int dt=0;dt<4;dt++) Oacc[dt] = (floatx4)0.0f;
  float lsum = 0.0f;

  const int srow = lane >> 3;          // 0..7
  const int scol = ((lane & 7) ^ srow) * 8;   // swizzled source chunk offset
  const int sw16 = l16 & 7;
  u16* PsW = Ps[wave];

  for (int mt=0; mt<SW_/64; ++mt){
    const int m0 = mt*64;
    __syncthreads();                   // prior-iter Ks/Vs reads complete
    #pragma unroll
    for (int c=0;c<2;c++){
      int rk = wave*8 + c*32 + srow;
      async_copy16(k  + ((long long)(b*SW_ + m0 + rk)*D_ + h*DH_) + scol,
                   Ks + (wave*8 + c*32)*64);
      async_copy16(vT + ((long long)(bh*DH_ + rk)*SW_ + m0) + scol,
                   Vs + (wave*8 + c*32)*64);
    }
    __syncthreads();                   // vmcnt drained -> tiles visible

    // S^T = K_tile . Q^T  (C layout: row = m-local = quad*4+r, col = q = l16)
    #pragma unroll
    for (int sub=0; sub<4; ++sub){
      short8 kf0 = *reinterpret_cast<const short8*>(Ks + (sub*16+l16)*64 + ((quad  ) ^ sw16)*8);
      short8 kf1 = *reinterpret_cast<const short8*>(Ks + (sub*16+l16)*64 + ((quad+4) ^ sw16)*8);
      floatx4 st = (floatx4)0.0f;
      st = __builtin_amdgcn_mfma_f32_16x16x32_bf16(kf0, qf0, st, 0,0,0);
      st = __builtin_amdgcn_mfma_f32_16x16x32_bf16(kf1, qf1, st, 0,0,0);
      float p0 = __expf(st[0]*0.125f);
      float p1 = __expf(st[1]*0.125f);
      float p2 = __expf(st[2]*0.125f);
      float p3 = __expf(st[3]*0.125f);
      lsum += (p0+p1) + (p2+p3);
      uint2 pk;
      pk.x = (unsigned)f2bf(p0) | ((unsigned)f2bf(p1) << 16);
      pk.y = (unsigned)f2bf(p2) | ((unsigned)f2bf(p3) << 16);
      *reinterpret_cast<uint2*>(PsW + l16*72 + sub*16 + quad*4) = pk;
    }

    // P A-fragments; same-wave LDS write->read is in-order, no barrier needed.
    short8 pf0 = *reinterpret_cast<const short8*>(PsW + l16*72 + quad*8);
    short8 pf1 = *reinterpret_cast<const short8*>(PsW + l16*72 + 32 + quad*8);

    // O[q][d] += P[q][m] . V[m][d]   (B-operand rows = V^T rows = d)
    #pragma unroll
    for (int dt=0; dt<4; ++dt){
      short8 vf0 = *reinterpret_cast<const short8*>(Vs + (dt*16+l16)*64 + ((quad  ) ^ sw16)*8);
      short8 vf1 = *reinterpret_cast<const short8*>(Vs + (dt*16+l16)*64 + ((quad+4) ^ sw16)*8);
      Oacc[dt] = __builtin_amdgcn_mfma_f32_16x16x32_bf16(pf0, vf0, Oacc[dt], 0,0,0);
      Oacc[dt] = __builtin_amdgcn_mfma_f32_16x16x32_bf16(pf1, vf1, Oacc[dt], 0,0,0);
    }
  }

  // denominator: lane holds partial sum for q = l16; reduce across quads
  lsum += __shfl_xor(lsum, 16);
  lsum += __shfl_xor(lsum, 32);

  #pragma unroll
  for (int r=0;r<4;r++){
    float linv = 1.0f / __shfl(lsum, quad*4 + r);   // l for q-row quad*4+r
    int qrow = qrow0 + quad*4 + r;
    #pragma unroll
    for (int dt=0;dt<4;dt++)
      o[((long long)(b*L_ + qrow))*D_ + h*DH_ + dt*16 + l16] = f2bf(Oacc[dt][r]*linv);
  }
}

// ---------------- launcher ----------------
extern "C" void kernel_launch(void* const* d_in, const int* in_sizes, int n_in,
                              void* d_out, int out_size, void* d_ws, size_t ws_size,
                              hipStream_t stream)
{
  const float* x     = (const float*)d_in[0];
  const float* gum   = (const float*)d_in[1];
  const float* ln1g  = (const float*)d_in[2];
  const float* ln1b  = (const float*)d_in[3];
  const float* ln2g  = (const float*)d_in[4];
  const float* ln2b  = (const float*)d_in[5];
  const float* wsal  = (const float*)d_in[6];
  const float* bsal  = (const float*)d_in[7];
  const float* inpw  = (const float*)d_in[8];
  const float* inpb  = (const float*)d_in[9];
  const float* outw  = (const float*)d_in[10];
  const float* outb  = (const float*)d_in[11];
  const float* wfc   = (const float*)d_in[12];
  const float* bfc   = (const float*)d_in[13];
  const float* wproj = (const float*)d_in[14];
  const float* bproj = (const float*)d_in[15];
  float* outp = (float*)d_out;
  char* ws = (char*)d_ws;

  const size_t BLD2 = (size_t)B_*L_*D_*2;     // 16 MB
  size_t off = 0;
  auto alloc = [&](size_t n){ char* p = ws + off; off += (n + 1023) & ~(size_t)1023; return p; };
  // persistent across phases
  u16*  WfcT   = (u16*)alloc((size_t)DFF_*D_*2);
  u16*  WprojT = (u16*)alloc((size_t)D_*DFF_*2);
  float* x2    = (float*)alloc((size_t)B_*L_*D_*4);
  float* logits= (float*)alloc(B_*NB_*4);
  int*  startb = (int*)alloc(S_*B_*4);
  char* regA = ws + off;
  // phase 1 (through out-proj GEMM)
  size_t o1 = 0;
  auto alloc1 = [&](size_t n){ char* p = regA + o1; o1 += (n + 1023) & ~(size_t)1023; return p; };
  u16* h_buf = (u16*)alloc1(BLD2);
  u16* Wqkv  = (u16*)alloc1((size_t)3*D_*D_*2);
  u16* Wout  = (u16*)alloc1((size_t)D_*D_*2);
  u16* qb    = (u16*)alloc1(BLD2);
  u16* kvb   = (u16*)alloc1((size_t)B_*SW_*D_*2);
  u16* kb    = (u16*)alloc1((size_t)B_*SW_*D_*2);
  u16* vTb   = (u16*)alloc1((size_t)B_*SW_*D_*2);
  u16* ob    = (u16*)alloc1(BLD2);
  // phase 2 (after out-proj) — reuses region A
  u16* h2b = (u16*)regA;
  u16* act = (u16*)(regA + ((BLD2 + 1023) & ~(size_t)1023));

  hipMemsetAsync(logits, 0, B_*NB_*4, stream);

  cast_f32_to_bf16<<<3*D_*D_/1024, 256, 0, stream>>>(inpw, Wqkv, 3*D_*D_/4);
  cast_f32_to_bf16<<<D_*D_/1024,   256, 0, stream>>>(outw, Wout, D_*D_/4);
  transpose_cast<<<dim3(DFF_/32, D_/32), 256, 0, stream>>>(wfc,   WfcT,   D_,   DFF_);
  transpose_cast<<<dim3(D_/32, DFF_/32), 256, 0, stream>>>(wproj, WprojT, DFF_, D_);

  ln_kernel<true><<<B_*L_, 256, 0, stream>>>(x, ln1g, ln1b, wsal, h_buf, logits);
  select_kernel<<<S_*B_, 64, 0, stream>>>(logits, gum, bsal, startb);
  gather_kv<<<B_*SW_, 256, 0, stream>>>(h_buf, startb, kvb);

  // Q projection (M=8192 -> 32 row-blocks of 256)
  gemm_bt<0><<<dim3(B_*L_/256,  D_/128), 256, 0, stream>>>(h_buf, Wqkv, inpb, nullptr, qb, nullptr, B_*L_, D_, D_);
  // merged K+V projection (M=2560 -> 10 blocks; N=2048); v written transposed
  gemm_bt<3><<<dim3(B_*SW_/256, 2*D_/128), 256, 0, stream>>>(kvb, Wqkv + D_*D_, inpb + D_, nullptr, kb, vTb, B_*SW_, 2*D_, D_);

  attn_kernel<<<dim3(B_*H_, L_/64), 256, 0, stream>>>(qb, kb, vTb, ob);

  gemm_bt<2><<<dim3(B_*L_/256, D_/128), 256, 0, stream>>>(ob, Wout, outb, x, x2, nullptr, B_*L_, D_, D_);

  ln_kernel<false><<<B_*L_, 256, 0, stream>>>(x2, ln2g, ln2b, nullptr, h2b, nullptr);

  gemm_bt<1><<<dim3(B_*L_/256, DFF_/128), 256, 0, stream>>>(h2b, WfcT,   bfc,   nullptr, act,  nullptr, B_*L_, DFF_, D_);
  gemm_bt<2><<<dim3(B_*L_/256, D_/128),   256, 0, stream>>>(act, WprojT, bproj, x2,      outp, nullptr, B_*L_, D_,   DFF_);
}

// Round 7
// 459.922 us; speedup vs baseline: 1.2251x; 1.2251x over previous
//
#include <hip/hip_runtime.h>

#define D_   1024
#define H_   16
#define DH_  64
#define S_   5
#define W_   128
#define BKB_ 32      // saliency block size
#define DFF_ 4096
#define B_   4
#define L_   2048
#define NB_  64
#define SW_  (S_*W_) // 640

typedef unsigned short u16;  // bf16 bit pattern
typedef __attribute__((ext_vector_type(8))) short short8;
typedef __attribute__((ext_vector_type(4))) float floatx4;

__device__ __forceinline__ u16 f2bf(float f){
  unsigned int u = __float_as_uint(f);
  unsigned int r = 0x7fffu + ((u >> 16) & 1u);
  return (u16)((u + r) >> 16);
}

__device__ __forceinline__ void async_copy16(const u16* g, u16* lds){
  __builtin_amdgcn_global_load_lds(
      (const __attribute__((address_space(1))) void*)g,
      (__attribute__((address_space(3))) void*)lds, 16, 0, 0);
}

// gelu(x) = 0.5x(1+tanh(u)) = x*t/(t+1), t = exp(2u); branch-free
__device__ __forceinline__ float gelu_fast(float x){
  float u2 = 1.5957691216057308f * x * __builtin_fmaf(0.044715f, x*x, 1.0f);
  u2 = fminf(u2, 20.0f);
  float t = __expf(u2);
  return x * t * __builtin_amdgcn_rcpf(t + 1.0f);
}

// ---------------- weight prep ----------------
__global__ void cast_f32_to_bf16(const float* __restrict__ in, u16* __restrict__ out, int n4){
  int i = blockIdx.x*256 + threadIdx.x;
  if (i < n4){
    float4 v = reinterpret_cast<const float4*>(in)[i];
    uint2 p;
    p.x = (unsigned)f2bf(v.x) | ((unsigned)f2bf(v.y) << 16);
    p.y = (unsigned)f2bf(v.z) | ((unsigned)f2bf(v.w) << 16);
    reinterpret_cast<uint2*>(out)[i] = p;
  }
}

// out[c][r] = in[r][c], out bf16 (C x R), in f32 (R x C)
__global__ void transpose_cast(const float* __restrict__ in, u16* __restrict__ out, int R, int C){
  __shared__ float t[32][33];
  int bx = blockIdx.x*32, by = blockIdx.y*32;
  int x = threadIdx.x & 31, y = threadIdx.x >> 5;   // y in 0..7
  #pragma unroll
  for (int i=0;i<4;i++)
    t[y + i*8][x] = in[(long long)(by + y + i*8)*C + bx + x];
  __syncthreads();
  #pragma unroll
  for (int i=0;i<4;i++)
    out[(long long)(bx + y + i*8)*R + by + x] = f2bf(t[x][y + i*8]);
}

// ---------------- layernorm (+ optional saliency row-dot) ----------------
template<bool ROWDOT>
__global__ __launch_bounds__(256) void ln_kernel(
    const float* __restrict__ x, const float* __restrict__ g, const float* __restrict__ b,
    const float* __restrict__ wsal, u16* __restrict__ out, float* __restrict__ logits)
{
  __shared__ float red[8];
  int row = blockIdx.x;
  int t = threadIdx.x;
  const float* xr = x + (long long)row*D_;
  float4 v = reinterpret_cast<const float4*>(xr)[t];
  float s  = v.x+v.y+v.z+v.w;
  float sq = v.x*v.x+v.y*v.y+v.z*v.z+v.w*v.w;
  #pragma unroll
  for (int m=32;m>=1;m>>=1){ s += __shfl_xor(s,m); sq += __shfl_xor(sq,m); }
  int wid = t>>6;
  if ((t&63)==0){ red[wid]=s; red[wid+4]=sq; }
  __syncthreads();
  s  = red[0]+red[1]+red[2]+red[3];
  sq = red[4]+red[5]+red[6]+red[7];
  float mean = s * (1.0f/D_);
  float var  = sq * (1.0f/D_) - mean*mean;
  float rstd = rsqrtf(fmaxf(var,0.0f) + 1e-5f);
  float4 gg = reinterpret_cast<const float4*>(g)[t];
  float4 bb = reinterpret_cast<const float4*>(b)[t];
  float h0 = (v.x-mean)*rstd*gg.x + bb.x;
  float h1 = (v.y-mean)*rstd*gg.y + bb.y;
  float h2 = (v.z-mean)*rstd*gg.z + bb.z;
  float h3 = (v.w-mean)*rstd*gg.w + bb.w;
  uint2 p;
  p.x = (unsigned)f2bf(h0) | ((unsigned)f2bf(h1) << 16);
  p.y = (unsigned)f2bf(h2) | ((unsigned)f2bf(h3) << 16);
  reinterpret_cast<uint2*>(out + (long long)row*D_)[t] = p;
  if (ROWDOT){
    float4 ww = reinterpret_cast<const float4*>(wsal)[t];
    float d = h0*ww.x + h1*ww.y + h2*ww.z + h3*ww.w;
    #pragma unroll
    for (int m=32;m>=1;m>>=1) d += __shfl_xor(d,m);
    __syncthreads();                     // red[] reuse guard
    if ((t&63)==0) red[wid] = d;
    __syncthreads();
    if (t==0)
      atomicAdd(logits + (row>>5), (red[0]+red[1]+red[2]+red[3]) * (1.0f/BKB_));
  }
}

// ---------------- gumbel argmax selection ----------------
__global__ void select_kernel(const float* __restrict__ logits, const float* __restrict__ gum,
                              const float* __restrict__ bsal, int* __restrict__ start)
{
  int s = blockIdx.x >> 2, b = blockIdx.x & 3;
  int n = threadIdx.x;                  // 0..63 (NB)
  float u = gum[(s*B_ + b)*NB_ + n];
  float g = -logf(-logf(u + 1e-9f) + 1e-9f);
  float val = logits[b*NB_ + n] + bsal[0] + g;   // TAU == 1
  int idx = n;
  #pragma unroll
  for (int m=1;m<64;m<<=1){
    float ov = __shfl_xor(val, m);
    int   oi = __shfl_xor(idx, m);
    if (ov > val || (ov == val && oi < idx)) { val = ov; idx = oi; }
  }
  if (n==0){
    int c = idx*BKB_ + BKB_/2 - W_/2;
    c = c < 0 ? 0 : (c > (L_-W_) ? (L_-W_) : c);
    start[blockIdx.x] = c;
  }
}

// ---------------- window gather: kv[b][s*W+w] = h[b][start[s][b]+w] ----------------
__global__ void gather_kv(const u16* __restrict__ h, const int* __restrict__ start, u16* __restrict__ kv){
  int row = blockIdx.x;                  // b*640 + s*128 + w
  int b = row / SW_; int sw = row % SW_; int s = sw >> 7; int w = sw & 127;
  long long src = (long long)(b*L_ + start[s*B_ + b] + w)*D_;
  reinterpret_cast<uint2*>(kv + (long long)row*D_)[threadIdx.x] =
      reinterpret_cast<const uint2*>(h + src)[threadIdx.x];
}

// -------- NT GEMM: C = A(MxK) * B(NxK)^T, 128x128 block, BK=64 dbuf --------
// Proven R4 geometry: 64x64 wave tiles, 128B LDS rows, swizzle
// phys_chunk = logical ^ (row&7) — measured ZERO SQ_LDS_BANK_CONFLICT.
// New: ping-pong LDS (2 x 32KB = 64KB, 2 blocks/CU): one barrier per K-iter;
// tile t+1's global_load_lds issued after the barrier, drained at the next
// barrier, so the whole MFMA phase covers the load latency.
// (R6 post-mortem: 256-wide tiles collapsed grid to 1 block/CU and its 64B-row
//  swizzle conflicted; reverted.)
// EPI: 0 = +bias->bf16 ; 1 = gelu(+bias)->bf16 ; 2 = +bias+res->f32 ;
//      3 = merged KV: col<1024 -> k(+bias)->bf16 ld1024; col>=1024 -> v(+bias)
//          written TRANSPOSED to Cout2 = vT[b][h][dh][m] (packed uint2 stores)
template<int EPI>
__global__ __launch_bounds__(256) void gemm_bt(
    const u16* __restrict__ A, const u16* __restrict__ Bm,
    const float* __restrict__ bias, const float* __restrict__ res,
    void* __restrict__ Cout, void* __restrict__ Cout2, int M, int N, int K)
{
  __shared__ u16 As[2][128*64];
  __shared__ u16 Bs[2][128*64];
  const int tid = threadIdx.x;
  const int wave = tid>>6, lane = tid&63;
  const int wr = wave>>1, wc = wave&1;
  const int quad = lane>>4, l16 = lane&15;
  const int rowA0 = blockIdx.x*128;
  const int colB0 = blockIdx.y*128;
  const int srow = wave*32 + (lane>>3);
  const int schunk = (lane&7) ^ ((lane>>3)&7);     // swizzled source chunk
  const u16* aP = A  + (long long)(rowA0 + srow)*K + schunk*8;
  const u16* bP = Bm + (long long)(colB0 + srow)*K + schunk*8;
  const int sw16 = l16 & 7;                        // row&7 for fragment reads
  floatx4 acc[4][4];
  #pragma unroll
  for (int i=0;i<4;i++)
    #pragma unroll
    for (int j=0;j<4;j++) acc[i][j] = (floatx4)0.0f;

  const int T = K >> 6;
  // prologue: tile 0 -> buffer 0
  #pragma unroll
  for (int t=0;t<4;t++){
    async_copy16(aP + (long long)t*8*K, &As[0][0] + wave*2048 + t*512);
    async_copy16(bP + (long long)t*8*K, &Bs[0][0] + wave*2048 + t*512);
  }

  for (int kt=0; kt<T; ++kt){
    __syncthreads();                 // drains tile kt's loads; frees buf (kt+1)&1
    if (kt+1 < T){
      const int nb = (kt+1)&1;
      const long long ko = (long long)(kt+1)*64;
      #pragma unroll
      for (int t=0;t<4;t++){
        async_copy16(aP + (long long)t*8*K + ko, &As[nb][0] + wave*2048 + t*512);
        async_copy16(bP + (long long)t*8*K + ko, &Bs[nb][0] + wave*2048 + t*512);
      }
    }
    const u16* Ab = &As[kt&1][0];
    const u16* Bb = &Bs[kt&1][0];
    #pragma unroll
    for (int ks=0;ks<2;ks++){
      const int cA = ((ks*4 + quad) ^ sw16) * 8;   // swizzled chunk offset
      short8 af[4], bfv[4];
      #pragma unroll
      for (int i=0;i<4;i++){
        af[i]  = *reinterpret_cast<const short8*>(Ab + (wr*64 + i*16 + l16)*64 + cA);
        bfv[i] = *reinterpret_cast<const short8*>(Bb + (wc*64 + i*16 + l16)*64 + cA);
      }
      #pragma unroll
      for (int i=0;i<4;i++)
        #pragma unroll
        for (int j=0;j<4;j++)
          acc[i][j] = __builtin_amdgcn_mfma_f32_16x16x32_bf16(af[i], bfv[j], acc[i][j], 0,0,0);
    }
  }

  #pragma unroll
  for (int i=0;i<4;i++){
    #pragma unroll
    for (int j=0;j<4;j++){
      int row0 = rowA0 + wr*64 + i*16 + quad*4;
      int col  = colB0 + wc*64 + j*16 + l16;
      float bc = bias[col];
      if (EPI==3){
        if (col < 1024){                       // k-part: ld 1024
          #pragma unroll
          for (int r=0;r<4;r++)
            ((u16*)Cout)[(long long)(row0+r)*1024 + col] = f2bf(acc[i][j][r] + bc);
        } else {                               // v-part: transposed, m-contiguous
          int vcol = col - 1024;
          int h = vcol >> 6, dh = vcol & 63;
          int b = row0 / SW_, mm = row0 % SW_;
          uint2 pk;
          pk.x = (unsigned)f2bf(acc[i][j][0]+bc) | ((unsigned)f2bf(acc[i][j][1]+bc) << 16);
          pk.y = (unsigned)f2bf(acc[i][j][2]+bc) | ((unsigned)f2bf(acc[i][j][3]+bc) << 16);
          *reinterpret_cast<uint2*>((u16*)Cout2 + ((long long)((b*H_ + h)*DH_ + dh))*SW_ + mm) = pk;
        }
      } else {
        #pragma unroll
        for (int r=0;r<4;r++){
          long long cidx = (long long)(row0+r)*N + col;
          float val = acc[i][j][r] + bc;
          if (EPI==0)      ((u16*)Cout)[cidx] = f2bf(val);
          else if (EPI==1) ((u16*)Cout)[cidx] = f2bf(gelu_fast(val));
          else             ((float*)Cout)[cidx] = val + res[cidx];
        }
      }
    }
  }
}

// ---------------- fused flash attention, S^T formulation ----------------
// grid (B*H, L/64); 4 waves, each wave owns 16 q-rows. m-tiles of 64 K/V rows.
__global__ __launch_bounds__(256) void attn_kernel(
    const u16* __restrict__ q, const u16* __restrict__ k, const u16* __restrict__ vT,
    u16* __restrict__ o)
{
  const int bh = blockIdx.x;
  const int b = bh >> 4, h = bh & 15;
  const int tid = threadIdx.x;
  const int wave = tid >> 6, lane = tid & 63;
  const int quad = lane >> 4, l16 = lane & 15;
  const int qrow0 = blockIdx.y*64 + wave*16;

  __shared__ u16 Ks[64*64];      // K rows (m-major, d contiguous, swizzled)
  __shared__ u16 Vs[64*64];      // V^T rows (d-major, m contiguous, swizzled)
  __shared__ u16 Ps[4][16*72];   // per-wave P (q-major, m contiguous, padded)

  // Q fragments (B-operand: lane l16 = q-row, quad*8 = d-chunk)
  const u16* qp = q + ((long long)(b*L_ + qrow0 + l16)*D_ + h*DH_ + quad*8);
  short8 qf0 = *reinterpret_cast<const short8*>(qp);
  short8 qf1 = *reinterpret_cast<const short8*>(qp + 32);

  floatx4 Oacc[4];
  #pragma unroll
  for (int dt=0;dt<4;dt++) Oacc[dt] = (floatx4)0.0f;
  float lsum = 0.0f;

  const int srow = lane >> 3;          // 0..7
  const int scol = ((lane & 7) ^ srow) * 8;   // swizzled source chunk offset
  const int sw16 = l16 & 7;
  u16* PsW = Ps[wave];

  for (int mt=0; mt<SW_/64; ++mt){
    const int m0 = mt*64;
    __syncthreads();                   // prior-iter Ks/Vs reads complete
    #pragma unroll
    for (int c=0;c<2;c++){
      int rk = wave*8 + c*32 + srow;
      async_copy16(k  + ((long long)(b*SW_ + m0 + rk)*D_ + h*DH_) + scol,
                   Ks + (wave*8 + c*32)*64);
      async_copy16(vT + ((long long)(bh*DH_ + rk)*SW_ + m0) + scol,
                   Vs + (wave*8 + c*32)*64);
    }
    __syncthreads();                   // vmcnt drained -> tiles visible

    // S^T = K_tile . Q^T  (C layout: row = m-local = quad*4+r, col = q = l16)
    #pragma unroll
    for (int sub=0; sub<4; ++sub){
      short8 kf0 = *reinterpret_cast<const short8*>(Ks + (sub*16+l16)*64 + ((quad  ) ^ sw16)*8);
      short8 kf1 = *reinterpret_cast<const short8*>(Ks + (sub*16+l16)*64 + ((quad+4) ^ sw16)*8);
      floatx4 st = (floatx4)0.0f;
      st = __builtin_amdgcn_mfma_f32_16x16x32_bf16(kf0, qf0, st, 0,0,0);
      st = __builtin_amdgcn_mfma_f32_16x16x32_bf16(kf1, qf1, st, 0,0,0);
      float p0 = __expf(st[0]*0.125f);
      float p1 = __expf(st[1]*0.125f);
      float p2 = __expf(st[2]*0.125f);
      float p3 = __expf(st[3]*0.125f);
      lsum += (p0+p1) + (p2+p3);
      uint2 pk;
      pk.x = (unsigned)f2bf(p0) | ((unsigned)f2bf(p1) << 16);
      pk.y = (unsigned)f2bf(p2) | ((unsigned)f2bf(p3) << 16);
      *reinterpret_cast<uint2*>(PsW + l16*72 + sub*16 + quad*4) = pk;
    }

    // P A-fragments; same-wave LDS write->read is in-order, no barrier needed.
    short8 pf0 = *reinterpret_cast<const short8*>(PsW + l16*72 + quad*8);
    short8 pf1 = *reinterpret_cast<const short8*>(PsW + l16*72 + 32 + quad*8);

    // O[q][d] += P[q][m] . V[m][d]   (B-operand rows = V^T rows = d)
    #pragma unroll
    for (int dt=0; dt<4; ++dt){
      short8 vf0 = *reinterpret_cast<const short8*>(Vs + (dt*16+l16)*64 + ((quad  ) ^ sw16)*8);
      short8 vf1 = *reinterpret_cast<const short8*>(Vs + (dt*16+l16)*64 + ((quad+4) ^ sw16)*8);
      Oacc[dt] = __builtin_amdgcn_mfma_f32_16x16x32_bf16(pf0, vf0, Oacc[dt], 0,0,0);
      Oacc[dt] = __builtin_amdgcn_mfma_f32_16x16x32_bf16(pf1, vf1, Oacc[dt], 0,0,0);
    }
  }

  // denominator: lane holds partial sum for q = l16; reduce across quads
  lsum += __shfl_xor(lsum, 16);
  lsum += __shfl_xor(lsum, 32);

  #pragma unroll
  for (int r=0;r<4;r++){
    float linv = 1.0f / __shfl(lsum, quad*4 + r);   // l for q-row quad*4+r
    int qrow = qrow0 + quad*4 + r;
    #pragma unroll
    for (int dt=0;dt<4;dt++)
      o[((long long)(b*L_ + qrow))*D_ + h*DH_ + dt*16 + l16] = f2bf(Oacc[dt][r]*linv);
  }
}

// ---------------- launcher ----------------
extern "C" void kernel_launch(void* const* d_in, const int* in_sizes, int n_in,
                              void* d_out, int out_size, void* d_ws, size_t ws_size,
                              hipStream_t stream)
{
  const float* x     = (const float*)d_in[0];
  const float* gum   = (const float*)d_in[1];
  const float* ln1g  = (const float*)d_in[2];
  const float* ln1b  = (const float*)d_in[3];
  const float* ln2g  = (const float*)d_in[4];
  const float* ln2b  = (const float*)d_in[5];
  const float* wsal  = (const float*)d_in[6];
  const float* bsal  = (const float*)d_in[7];
  const float* inpw  = (const float*)d_in[8];
  const float* inpb  = (const float*)d_in[9];
  const float* outw  = (const float*)d_in[10];
  const float* outb  = (const float*)d_in[11];
  const float* wfc   = (const float*)d_in[12];
  const float* bfc   = (const float*)d_in[13];
  const float* wproj = (const float*)d_in[14];
  const float* bproj = (const float*)d_in[15];
  float* outp = (float*)d_out;
  char* ws = (char*)d_ws;

  const size_t BLD2 = (size_t)B_*L_*D_*2;     // 16 MB
  size_t off = 0;
  auto alloc = [&](size_t n){ char* p = ws + off; off += (n + 1023) & ~(size_t)1023; return p; };
  // persistent across phases
  u16*  WfcT   = (u16*)alloc((size_t)DFF_*D_*2);
  u16*  WprojT = (u16*)alloc((size_t)D_*DFF_*2);
  float* x2    = (float*)alloc((size_t)B_*L_*D_*4);
  float* logits= (float*)alloc(B_*NB_*4);
  int*  startb = (int*)alloc(S_*B_*4);
  char* regA = ws + off;
  // phase 1 (through out-proj GEMM)
  size_t o1 = 0;
  auto alloc1 = [&](size_t n){ char* p = regA + o1; o1 += (n + 1023) & ~(size_t)1023; return p; };
  u16* h_buf = (u16*)alloc1(BLD2);
  u16* Wqkv  = (u16*)alloc1((size_t)3*D_*D_*2);
  u16* Wout  = (u16*)alloc1((size_t)D_*D_*2);
  u16* qb    = (u16*)alloc1(BLD2);
  u16* kvb   = (u16*)alloc1((size_t)B_*SW_*D_*2);
  u16* kb    = (u16*)alloc1((size_t)B_*SW_*D_*2);
  u16* vTb   = (u16*)alloc1((size_t)B_*SW_*D_*2);
  u16* ob    = (u16*)alloc1(BLD2);
  // phase 2 (after out-proj) — reuses region A
  u16* h2b = (u16*)regA;
  u16* act = (u16*)(regA + ((BLD2 + 1023) & ~(size_t)1023));

  hipMemsetAsync(logits, 0, B_*NB_*4, stream);

  cast_f32_to_bf16<<<3*D_*D_/1024, 256, 0, stream>>>(inpw, Wqkv, 3*D_*D_/4);
  cast_f32_to_bf16<<<D_*D_/1024,   256, 0, stream>>>(outw, Wout, D_*D_/4);
  transpose_cast<<<dim3(DFF_/32, D_/32), 256, 0, stream>>>(wfc,   WfcT,   D_,   DFF_);
  transpose_cast<<<dim3(D_/32, DFF_/32), 256, 0, stream>>>(wproj, WprojT, DFF_, D_);

  ln_kernel<true><<<B_*L_, 256, 0, stream>>>(x, ln1g, ln1b, wsal, h_buf, logits);
  select_kernel<<<S_*B_, 64, 0, stream>>>(logits, gum, bsal, startb);
  gather_kv<<<B_*SW_, 256, 0, stream>>>(h_buf, startb, kvb);

  // Q projection
  gemm_bt<0><<<dim3(B_*L_/128,  D_/128), 256, 0, stream>>>(h_buf, Wqkv, inpb, nullptr, qb, nullptr, B_*L_, D_, D_);
  // merged K+V projection (N=2048 over stacked wk|wv); v written transposed
  gemm_bt<3><<<dim3(B_*SW_/128, 2*D_/128), 256, 0, stream>>>(kvb, Wqkv + D_*D_, inpb + D_, nullptr, kb, vTb, B_*SW_, 2*D_, D_);

  attn_kernel<<<dim3(B_*H_, L_/64), 256, 0, stream>>>(qb, kb, vTb, ob);

  gemm_bt<2><<<dim3(B_*L_/128, D_/128), 256, 0, stream>>>(ob, Wout, outb, x, x2, nullptr, B_*L_, D_, D_);

  ln_kernel<false><<<B_*L_, 256, 0, stream>>>(x2, ln2g, ln2b, nullptr, h2b, nullptr);

  gemm_bt<1><<<dim3(B_*L_/128, DFF_/128), 256, 0, stream>>>(h2b, WfcT,   bfc,   nullptr, act,  nullptr, B_*L_, DFF_, D_);
  gemm_bt<2><<<dim3(B_*L_/128, D_/128),   256, 0, stream>>>(act, WprojT, bproj, x2,      outp, nullptr, B_*L_, D_,   DFF_);
}